// Round 1
// baseline (128.210 us; speedup 1.0000x reference)
//
#include <hip/hip_runtime.h>
#include <math.h>

#define EPS 1e-9f

__device__ __forceinline__ float2 wave_reduce_f2(float2 v) {
    #pragma unroll
    for (int off = 32; off > 0; off >>= 1) {
        v.x += __shfl_down(v.x, off, 64);
        v.y += __shfl_down(v.y, off, 64);
    }
    return v;
}

// One wave (64 lanes) per circle. Lanes strip-mine the j loops, then
// shuffle-reduce the float2 correction.
__global__ void circles_kernel(const float2* __restrict__ cpos,
                               const float*  __restrict__ crad,
                               const float2* __restrict__ apos,
                               const float2* __restrict__ ahalf,
                               float2* __restrict__ out,
                               int Nc, int Na) {
    const int gtid = blockIdx.x * blockDim.x + threadIdx.x;
    const int wave = gtid >> 6;
    const int lane = threadIdx.x & 63;
    if (wave >= Nc) return;
    const int i = wave;

    const float2 pi = cpos[i];
    const float  ri = crad[i];
    float2 acc = make_float2(0.0f, 0.0f);

    // ---- circle vs circle ----
    for (int j = lane; j < Nc; j += 64) {
        const float2 pj = cpos[j];
        const float  rj = crad[j];
        const float dx = pi.x - pj.x;
        const float dy = pi.y - pj.y;
        const float d2 = dx * dx + dy * dy;
        if (j != i && d2 > EPS) {
            const float dist = sqrtf(d2);
            const float pen  = ri + rj - dist;
            if (pen > 0.0f) {
                const float s = 0.5f * pen / dist;
                acc.x += s * dx;
                acc.y += s * dy;
            }
        }
    }

    // ---- circle vs aabb (push on circle) ----
    for (int j = lane; j < Na; j += 64) {
        const float2 aj = apos[j];
        const float2 hj = ahalf[j];
        const float rx = pi.x - aj.x;
        const float ry = pi.y - aj.y;
        const float cx = fminf(fmaxf(rx, -hj.x), hj.x);
        const float cy = fminf(fmaxf(ry, -hj.y), hj.y);
        const float dx = rx - cx;
        const float dy = ry - cy;
        const float d2 = dx * dx + dy * dy;
        if (d2 > EPS) {
            const float dist = sqrtf(d2);
            const float pen  = ri - dist;
            if (pen > 0.0f) {
                const float s = 0.5f * pen / dist;
                acc.x += s * dx;
                acc.y += s * dy;
            }
        }
    }

    acc = wave_reduce_f2(acc);
    if (lane == 0) {
        out[i] = make_float2(pi.x + acc.x, pi.y + acc.y);
    }
}

// One wave per aabb. aabb-aabb minimum-axis push + equal-and-opposite
// circle-aabb push.
__global__ void aabbs_kernel(const float2* __restrict__ cpos,
                             const float*  __restrict__ crad,
                             const float2* __restrict__ apos,
                             const float2* __restrict__ ahalf,
                             float2* __restrict__ out,
                             int Nc, int Na) {
    const int gtid = blockIdx.x * blockDim.x + threadIdx.x;
    const int wave = gtid >> 6;
    const int lane = threadIdx.x & 63;
    if (wave >= Na) return;
    const int i = wave;

    const float2 ai = apos[i];
    const float2 hi = ahalf[i];
    float2 acc = make_float2(0.0f, 0.0f);

    // ---- aabb vs aabb ----
    for (int j = lane; j < Na; j += 64) {
        const float2 aj = apos[j];
        const float2 hj = ahalf[j];
        const float dax = ai.x - aj.x;
        const float day = ai.y - aj.y;
        const float ovx = hi.x + hj.x - fabsf(dax);
        const float ovy = hi.y + hj.y - fabsf(day);
        if (j != i && ovx > 0.0f && ovy > 0.0f) {
            if (ovx <= ovy) {
                acc.x += 0.5f * ovx * (dax >= 0.0f ? 1.0f : -1.0f);
            } else {
                acc.y += 0.5f * ovy * (day >= 0.0f ? 1.0f : -1.0f);
            }
        }
    }

    // ---- circle vs aabb (equal-and-opposite on the box) ----
    for (int j = lane; j < Nc; j += 64) {
        const float2 pj = cpos[j];
        const float  rj = crad[j];
        const float rx = pj.x - ai.x;
        const float ry = pj.y - ai.y;
        const float cx = fminf(fmaxf(rx, -hi.x), hi.x);
        const float cy = fminf(fmaxf(ry, -hi.y), hi.y);
        const float dx = rx - cx;
        const float dy = ry - cy;
        const float d2 = dx * dx + dy * dy;
        if (d2 > EPS) {
            const float dist = sqrtf(d2);
            const float pen  = rj - dist;
            if (pen > 0.0f) {
                const float s = 0.5f * pen / dist;
                acc.x -= s * dx;
                acc.y -= s * dy;
            }
        }
    }

    acc = wave_reduce_f2(acc);
    if (lane == 0) {
        out[Nc + i] = make_float2(ai.x + acc.x, ai.y + acc.y);
    }
}

extern "C" void kernel_launch(void* const* d_in, const int* in_sizes, int n_in,
                              void* d_out, int out_size, void* d_ws, size_t ws_size,
                              hipStream_t stream) {
    (void)n_in; (void)out_size; (void)d_ws; (void)ws_size;

    const float2* cpos  = (const float2*)d_in[0];
    const float*  crad  = (const float*) d_in[1];
    const float2* apos  = (const float2*)d_in[2];
    const float2* ahalf = (const float2*)d_in[3];
    float2* out = (float2*)d_out;

    const int Nc = in_sizes[1];       // circle_radius flat count = Nc
    const int Na = in_sizes[2] / 2;   // aabb_pos flat count = Na*2

    // one wave per body, 4 waves (256 threads) per block
    const int block = 256;
    const int waves_per_block = block / 64;

    const int grid_c = (Nc + waves_per_block - 1) / waves_per_block;
    circles_kernel<<<grid_c, block, 0, stream>>>(cpos, crad, apos, ahalf, out, Nc, Na);

    const int grid_a = (Na + waves_per_block - 1) / waves_per_block;
    aabbs_kernel<<<grid_a, block, 0, stream>>>(cpos, crad, apos, ahalf, out, Nc, Na);
}

// Round 2
// 80.112 us; speedup vs baseline: 1.6004x; 1.6004x over previous
//
#include <hip/hip_runtime.h>
#include <math.h>

#define EPS 1e-9f

// out[i] = body position (concat circles then boxes); atomics accumulate corrections on top.
__global__ void init_out(const float2* __restrict__ cpos,
                         const float2* __restrict__ apos,
                         float2* __restrict__ out, int Nc, int Ntot) {
    int i = blockIdx.x * blockDim.x + threadIdx.x;
    if (i < Ntot) out[i] = (i < Nc) ? cpos[i] : apos[i - Nc];
}

// Lane-per-body, chunked j-space.
//   blockIdx.x : body-group (4 waves/block, 64 bodies/wave)
//   blockIdx.y : j-chunk
// Each body sees a unified partner space of size Ntot = Nc + Na:
//   circles: [0,Nc) = circle partners, [Nc,Ntot) = box partners
//   boxes:   [0,Na) = box partners,    [Na,Ntot) = circle partners
// j-loop indices are lane-invariant -> scalar loads; pair math is branchless
// (cndmask), sqrt+div replaced by one v_rsq_f32.
__global__ __launch_bounds__(256)
void collide(const float2* __restrict__ cpos,
             const float*  __restrict__ crad,
             const float2* __restrict__ apos,
             const float2* __restrict__ ahalf,
             float* __restrict__ out,
             int Nc, int Na, int S) {
    const int lane = threadIdx.x & 63;
    const int grp  = blockIdx.x * 4 + (threadIdx.x >> 6);
    const int i    = (grp << 6) + lane;
    const int Ntot = Nc + Na;
    if (i >= Ntot) return;

    const int j0 = blockIdx.y * S;
    const int j1 = min(j0 + S, Ntot);

    float ax = 0.0f, ay = 0.0f;

    if (i < Nc) {
        const float2 p  = cpos[i];
        const float  ri = crad[i];

        // circle vs circle
        const int e = min(j1, Nc);
        #pragma unroll 4
        for (int j = j0; j < e; ++j) {
            const float2 q  = cpos[j];
            const float  rj = crad[j];
            const float dx = p.x - q.x, dy = p.y - q.y;
            const float d2 = fmaf(dx, dx, dy * dy);
            const float r  = __builtin_amdgcn_rsqf(d2);
            const float dist = d2 * r;                 // ~sqrt(d2)
            const float pen  = ri + rj - dist;
            const bool ok = (j != i) && (d2 > EPS) && (pen > 0.0f);
            const float s = ok ? 0.5f * pen * r : 0.0f;
            ax = fmaf(s, dx, ax);
            ay = fmaf(s, dy, ay);
        }
        // circle vs box (push on circle)
        const int b0 = max(j0, Nc) - Nc, b1 = j1 - Nc;
        #pragma unroll 4
        for (int j = b0; j < b1; ++j) {
            const float2 q = apos[j];
            const float2 h = ahalf[j];
            const float rx = p.x - q.x, ry = p.y - q.y;
            const float cx = fminf(fmaxf(rx, -h.x), h.x);
            const float cy = fminf(fmaxf(ry, -h.y), h.y);
            const float dx = rx - cx, dy = ry - cy;
            const float d2 = fmaf(dx, dx, dy * dy);
            const float r  = __builtin_amdgcn_rsqf(d2);
            const float pen = ri - d2 * r;
            const bool ok = (d2 > EPS) && (pen > 0.0f);
            const float s = ok ? 0.5f * pen * r : 0.0f;
            ax = fmaf(s, dx, ax);
            ay = fmaf(s, dy, ay);
        }
    } else {
        const int ib = i - Nc;
        const float2 a = apos[ib];
        const float2 h = ahalf[ib];

        // box vs box (minimum-overlap axis)
        const int e = min(j1, Na);
        #pragma unroll 4
        for (int j = j0; j < e; ++j) {
            const float2 q  = apos[j];
            const float2 hj = ahalf[j];
            const float dax = a.x - q.x, day = a.y - q.y;
            const float ovx = h.x + hj.x - fabsf(dax);
            const float ovy = h.y + hj.y - fabsf(day);
            const bool hit = (j != ib) && (ovx > 0.0f) && (ovy > 0.0f);
            const bool ux  = ovx <= ovy;
            ax += (hit && ux)  ? 0.5f * ovx * (dax >= 0.0f ? 1.0f : -1.0f) : 0.0f;
            ay += (hit && !ux) ? 0.5f * ovy * (day >= 0.0f ? 1.0f : -1.0f) : 0.0f;
        }
        // circle vs box (equal-and-opposite on box)
        const int c0 = max(j0, Na) - Na, c1 = j1 - Na;
        #pragma unroll 4
        for (int j = c0; j < c1; ++j) {
            const float2 q  = cpos[j];
            const float  rj = crad[j];
            const float rx = q.x - a.x, ry = q.y - a.y;
            const float cx = fminf(fmaxf(rx, -h.x), h.x);
            const float cy = fminf(fmaxf(ry, -h.y), h.y);
            const float dx = rx - cx, dy = ry - cy;
            const float d2 = fmaf(dx, dx, dy * dy);
            const float r  = __builtin_amdgcn_rsqf(d2);
            const float pen = rj - d2 * r;
            const bool ok = (d2 > EPS) && (pen > 0.0f);
            const float s = ok ? -0.5f * pen * r : 0.0f;   // opposite sign on the box
            ax = fmaf(s, dx, ax);
            ay = fmaf(s, dy, ay);
        }
    }

    atomicAdd(&out[2 * i],     ax);
    atomicAdd(&out[2 * i + 1], ay);
}

extern "C" void kernel_launch(void* const* d_in, const int* in_sizes, int n_in,
                              void* d_out, int out_size, void* d_ws, size_t ws_size,
                              hipStream_t stream) {
    (void)n_in; (void)out_size; (void)d_ws; (void)ws_size;

    const float2* cpos  = (const float2*)d_in[0];
    const float*  crad  = (const float*) d_in[1];
    const float2* apos  = (const float2*)d_in[2];
    const float2* ahalf = (const float2*)d_in[3];

    const int Nc   = in_sizes[1];       // circle count
    const int Na   = in_sizes[2] / 2;   // box count
    const int Ntot = Nc + Na;

    // init: out = positions
    init_out<<<(Ntot + 255) / 256, 256, 0, stream>>>(cpos, apos, (float2*)d_out, Nc, Ntot);

    // main: lane-per-body x j-chunks
    const int groups = (Ntot + 63) / 64;          // 96
    const int gx     = (groups + 3) / 4;          // 4 waves/block
    const int C      = 64;                        // j-chunks
    const int S      = (Ntot + C - 1) / C;        // 96 partners/chunk
    dim3 grid(gx, C, 1);
    collide<<<grid, 256, 0, stream>>>(cpos, crad, apos, ahalf, (float*)d_out, Nc, Na, S);
}